// Round 5
// baseline (209.061 us; speedup 1.0000x reference)
//
#include <hip/hip_runtime.h>
#include <stdint.h>

#define B_ 64
#define P_ 32768
#define O_ 16
#define PPT 4                 // priors per thread in match_kernel
#define BPT 8                 // priors per thread in best_prior_kernel

constexpr float OVERLAP_THRESH = 0.5f;
constexpr int   NEG_POS_RATIO  = 3;
constexpr float VAR0 = 0.1f;
constexpr float VAR1 = 0.2f;

// ---------------------------------------------------------------------------
// Kernel 1: best prior per (b,o) = argmax_p IoU. Division-free running best
// (in,un,p) per truth per thread; one f32 division per (thread,truth) at the
// end; merge via LDS atomicMax(u64) then global atomicMax. Pack =
// (iou_bits<<32)|~p (iou>=0 -> monotonic bits; ~p = lowest index wins ties).
// bp_pack must be pre-zeroed (pack 0 = iou 0, p = 0xffffffff).
// ---------------------------------------------------------------------------
__global__ __launch_bounds__(256)
void best_prior_kernel(const float* __restrict__ priors,
                       const float* __restrict__ targets,
                       unsigned long long* __restrict__ bp_pack) {
    int b   = blockIdx.y;
    int tid = threadIdx.x;
    int p0  = blockIdx.x * (256 * BPT) + tid;
    const float* tb = targets + (size_t)b * O_ * 5;   // uniform -> s_load

    float bi[O_], bu[O_];
    int   bp_[O_];
    #pragma unroll
    for (int o = 0; o < O_; ++o) { bi[o] = 0.f; bu[o] = 1.f; bp_[o] = p0; }

    #pragma unroll
    for (int j = 0; j < BPT; ++j) {
        int p = p0 + j * 256;
        float4 pr = ((const float4*)priors)[p];
        float px0 = pr.x - pr.z * 0.5f, py0 = pr.y - pr.w * 0.5f;
        float px1 = pr.x + pr.z * 0.5f, py1 = pr.y + pr.w * 0.5f;
        float pa  = (px1 - px0) * (py1 - py0);
        #pragma unroll
        for (int o = 0; o < O_; ++o) {
            float tx0 = tb[o * 5 + 0], ty0 = tb[o * 5 + 1];
            float tx1 = tb[o * 5 + 2], ty1 = tb[o * 5 + 3];
            float ta  = (tx1 - tx0) * (ty1 - ty0);
            float w = fmaxf(fminf(tx1, px1) - fmaxf(tx0, px0), 0.f);
            float h = fmaxf(fminf(ty1, py1) - fmaxf(ty0, py0), 0.f);
            float in_ = w * h;
            float un_ = ta + pa - in_;
            bool gt = in_ * bu[o] > bi[o] * un_;
            bi[o]  = gt ? in_ : bi[o];
            bu[o]  = gt ? un_ : bu[o];
            bp_[o] = gt ? p   : bp_[o];
        }
    }

    __shared__ unsigned long long sbp[O_];
    if (tid < O_) sbp[tid] = 0ull;
    __syncthreads();
    #pragma unroll
    for (int o = 0; o < O_; ++o) {
        float iou = bi[o] / bu[o];   // IEEE f32 div, matches reference rounding
        unsigned long long pack =
            ((unsigned long long)__float_as_uint(iou) << 32) | (unsigned)(~bp_[o]);
        atomicMax(&sbp[o], pack);
    }
    __syncthreads();
    if (tid < O_) atomicMax(&bp_pack[(size_t)b * O_ + tid], sbp[tid]);
}

// ---------------------------------------------------------------------------
// Kernel 2: per (b, prior p): match, encode, smooth-L1, CE, rank_src.
// Truths/bp read via uniform (SGPR) loads — no LDS staging, no entry barrier.
// Division-free matching; truths-outer / priors-inner for ILP.
// ---------------------------------------------------------------------------
__device__ __forceinline__ float sl1(float d) {
    float ad = fabsf(d);
    return (ad < 1.f) ? 0.5f * d * d : ad - 0.5f;
}

__global__ __launch_bounds__(256)
void match_kernel(const float* __restrict__ loc_data,
                  const float* __restrict__ conf_data,
                  const float* __restrict__ priors,
                  const float* __restrict__ targets,
                  const unsigned* __restrict__ bp_lo,   // bp_pack viewed as u32
                  float* __restrict__ rank,
                  int* __restrict__ num_pos,
                  double* __restrict__ acc) {
    int b   = blockIdx.y;
    int tid = threadIdx.x;
    int p0  = blockIdx.x * (256 * PPT) + tid;
    const float* tb = targets + (size_t)b * O_ * 5;   // uniform -> s_load

    float px0[PPT], py0[PPT], px1[PPT], py1[PPT], pa[PPT];
    float cx[PPT], cy[PPT], pz[PPT], pw[PPT];
    float2 cd[PPT];
    float ib[PPT], ub[PPT];
    int   idx[PPT], fidx[PPT];
    bool  fset[PPT];

    #pragma unroll
    for (int j = 0; j < PPT; ++j) {
        int p = p0 + j * 256;
        float4 pr = ((const float4*)priors)[p];
        cd[j] = ((const float2*)conf_data)[(size_t)b * P_ + p];
        cx[j] = pr.x; cy[j] = pr.y; pz[j] = pr.z; pw[j] = pr.w;
        px0[j] = pr.x - pr.z * 0.5f; py0[j] = pr.y - pr.w * 0.5f;
        px1[j] = pr.x + pr.z * 0.5f; py1[j] = pr.y + pr.w * 0.5f;
        pa[j]  = (px1[j] - px0[j]) * (py1[j] - py0[j]);
        ib[j] = 0.f; ub[j] = 1.f; idx[j] = 0; fidx[j] = 0; fset[j] = false;
    }

    #pragma unroll
    for (int o = 0; o < O_; ++o) {
        float tx0 = tb[o * 5 + 0], ty0 = tb[o * 5 + 1];
        float tx1 = tb[o * 5 + 2], ty1 = tb[o * 5 + 3];
        float ta  = (tx1 - tx0) * (ty1 - ty0);
        int bp = (int)~bp_lo[((size_t)b * O_ + o) * 2];  // low dword (LE)
        #pragma unroll
        for (int j = 0; j < PPT; ++j) {
            float w = fmaxf(fminf(tx1, px1[j]) - fmaxf(tx0, px0[j]), 0.f);
            float h = fmaxf(fminf(ty1, py1[j]) - fmaxf(ty0, py0[j]), 0.f);
            float in_ = w * h;
            float un_ = ta + pa[j] - in_;
            bool gt = in_ * ub[j] > ib[j] * un_;
            ib[j]  = gt ? in_ : ib[j];
            ub[j]  = gt ? un_ : ub[j];
            idx[j] = gt ? o : idx[j];
            bool hit = (bp == p0 + j * 256);
            fidx[j] = hit ? o : fidx[j];
            fset[j] |= hit;
        }
    }

    double lld = 0.0, ce_pos = 0.0;
    int pc = 0;

    #pragma unroll
    for (int j = 0; j < PPT; ++j) {
        int p = p0 + j * 256;
        size_t gi = (size_t)b * P_ + p;
        bool pos = fset[j] || (2.0f * ib[j] >= ub[j]);
        int mi = fset[j] ? fidx[j] : idx[j];

        float m   = fmaxf(cd[j].x, cd[j].y);
        float ad  = fabsf(cd[j].x - cd[j].y);
        float lse = m + __logf(1.0f + __expf(-ad));
        float cgt = pos ? cd[j].y : cd[j].x;
        float ce  = lse - cgt;

        rank[gi] = pos ? 0.f : ce;

        if (pos) {
            float mx0 = tb[mi * 5 + 0], my0 = tb[mi * 5 + 1];
            float mx1 = tb[mi * 5 + 2], my1 = tb[mi * 5 + 3];
            float gcx = ((mx0 + mx1) * 0.5f - cx[j]) / (VAR0 * pz[j]);
            float gcy = ((my0 + my1) * 0.5f - cy[j]) / (VAR0 * pw[j]);
            float gw  = __logf((mx1 - mx0) / pz[j]) * (1.0f / VAR1);
            float gh  = __logf((my1 - my0) / pw[j]) * (1.0f / VAR1);
            float4 ld = ((const float4*)loc_data)[gi];
            float ll = sl1(ld.x - gcx) + sl1(ld.y - gcy) +
                       sl1(ld.z - gw)  + sl1(ld.w - gh);
            lld    += (double)ll;
            ce_pos += (double)ce;
            pc     += 1;
        }
    }

    for (int off = 32; off; off >>= 1) {
        lld    += __shfl_down(lld, off, 64);
        ce_pos += __shfl_down(ce_pos, off, 64);
        pc     += __shfl_down(pc, off, 64);
    }
    __shared__ double sll[4], sce[4];
    __shared__ int    spc[4];
    int wid = tid >> 6;
    if ((tid & 63) == 0) { sll[wid] = lld; sce[wid] = ce_pos; spc[wid] = pc; }
    __syncthreads();
    if (tid == 0) {
        double tl = sll[0] + sll[1] + sll[2] + sll[3];
        double tc = sce[0] + sce[1] + sce[2] + sce[3];
        int    tp = spc[0] + spc[1] + spc[2] + spc[3];
        if (tl != 0.0) atomicAdd(&acc[0], tl);
        if (tc != 0.0) atomicAdd(&acc[1], tc);
        if (tp)        atomicAdd(&num_pos[b], tp);
    }
}

// ---------------------------------------------------------------------------
// Kernel 3: per batch, exact top-k sum via 11/11/10-bit radix select
// (3 levels, 2048 bins: ~8x less same-address atomic contention on the hot
// exponent bins than 8-bit, and one fewer pass). Keys register-resident.
// Suffix-scan: lane-local + wave shfl + cross-wave via LDS.
// top-k sum = sum(values > kth) + (k - count_greater) * kth  (tie-exact).
// Values are CE >= 0 -> bit31 = 0 -> level-0 bin < 1024 < 2048.
// ---------------------------------------------------------------------------
__global__ __launch_bounds__(1024)
void topk_kernel(const float* __restrict__ rank,
                 const int* __restrict__ num_pos,
                 double* __restrict__ acc) {
    int b   = blockIdx.x;
    int tid = threadIdx.x;
    int np  = num_pos[b];
    int k   = min(NEG_POS_RATIO * np, P_ - 1);
    if (k <= 0) return;

    const uint4* r4 = (const uint4*)(rank + (size_t)b * P_);
    unsigned key[32];
    #pragma unroll
    for (int j = 0; j < 8; ++j) {
        uint4 v = r4[j * 1024 + tid];
        key[j * 4 + 0] = v.x; key[j * 4 + 1] = v.y;
        key[j * 4 + 2] = v.z; key[j * 4 + 3] = v.w;
    }

    __shared__ unsigned cnt[2048];
    __shared__ unsigned wsum[16];
    __shared__ unsigned s_pre;
    __shared__ int      s_k;

    int lane = tid & 63, wid = tid >> 6;
    unsigned pre = 0;   // selected high bits so far (right-aligned)
    int kk = k;

    #pragma unroll
    for (int level = 0; level < 3; ++level) {
        const int shift = (level == 0) ? 21 : (level == 1) ? 10 : 0;
        const int hishf = (level == 1) ? 21 : 10;           // unused at level 0
        const unsigned fmask = (level == 2) ? 0x3FFu : 0x7FFu;
        const int nb = (level == 2) ? 1024 : 2048;

        cnt[tid] = 0; cnt[tid + 1024] = 0;
        __syncthreads();

        if (level == 0) {
            #pragma unroll
            for (int j = 0; j < 32; ++j)
                atomicAdd(&cnt[key[j] >> 21], 1u);
        } else {
            #pragma unroll
            for (int j = 0; j < 32; ++j) {
                unsigned u = key[j];
                if ((u >> hishf) == pre) atomicAdd(&cnt[(u >> shift) & fmask], 1u);
            }
        }
        __syncthreads();

        // suffix scan: thread t owns bins 2t, 2t+1 (zero beyond nb)
        unsigned c1 = (2 * tid + 1 < nb) ? cnt[2 * tid + 1] : 0u;
        unsigned c0 = ((2 * tid < nb) ? cnt[2 * tid] : 0u) + c1;  // S local
        unsigned g = c0, G = g;
        #pragma unroll
        for (int off = 1; off < 64; off <<= 1) {
            unsigned r = __shfl_down(G, off, 64);
            if (lane + off < 64) G += r;
        }
        if (lane == 0) wsum[wid] = G;
        __syncthreads();
        unsigned T = 0;
        for (int w = wid + 1; w < 16; ++w) T += wsum[w];
        unsigned A  = (G - g) + T;       // sum of bins > 2t+1
        unsigned S1 = A + c1;            // suffix sum from bin 2t+1
        unsigned S0 = A + c0;            // suffix sum from bin 2t
        unsigned ukk = (unsigned)kk;
        if (2 * tid + 1 < nb && S1 >= ukk && A < ukk) {
            s_pre = (unsigned)(2 * tid + 1); s_k = kk - (int)A;
        } else if (2 * tid < nb && S0 >= ukk && S1 < ukk) {
            s_pre = (unsigned)(2 * tid);     s_k = kk - (int)S1;
        }
        __syncthreads();
        pre = (pre << ((level == 2) ? 10 : 11)) | s_pre;
        kk  = s_k;
        __syncthreads();   // cnt reused next level
    }

    unsigned kth = pre;   // exact bits of the k-th largest value
    double sum = 0.0;
    int cg = 0;
    #pragma unroll
    for (int j = 0; j < 32; ++j) {
        unsigned u = key[j];
        if (u > kth) { sum += (double)__uint_as_float(u); ++cg; }
    }
    for (int off = 32; off; off >>= 1) {
        sum += __shfl_down(sum, off, 64);
        cg  += __shfl_down(cg, off, 64);
    }
    __shared__ double ssum[16];
    __shared__ int    scg[16];
    if (lane == 0) { ssum[wid] = sum; scg[wid] = cg; }
    __syncthreads();
    if (tid == 0) {
        double tsum = 0.0; int tcg = 0;
        for (int i = 0; i < 16; ++i) { tsum += ssum[i]; tcg += scg[i]; }
        double total = tsum + (double)(k - tcg) * (double)__uint_as_float(kth);
        atomicAdd(&acc[2], total);
    }
}

// ---------------------------------------------------------------------------
// Kernel 4: finalize
// ---------------------------------------------------------------------------
__global__ void finalize_kernel(const int* __restrict__ num_pos,
                                const double* __restrict__ acc,
                                float* __restrict__ out) {
    if (threadIdx.x == 0 && blockIdx.x == 0) {
        int N = 0;
        for (int b = 0; b < B_; ++b) N += num_pos[b];
        double Nd = (double)N;
        out[0] = (float)(acc[0] / Nd);
        out[1] = (float)((acc[1] + acc[2]) / Nd);
    }
}

extern "C" void kernel_launch(void* const* d_in, const int* in_sizes, int n_in,
                              void* d_out, int out_size, void* d_ws, size_t ws_size,
                              hipStream_t stream) {
    const float* loc_data  = (const float*)d_in[0];
    const float* conf_data = (const float*)d_in[1];
    const float* priors    = (const float*)d_in[2];
    const float* targets   = (const float*)d_in[3];

    char* ws = (char*)d_ws;
    // layout: [bp_pack 8KB][num_pos 256B][acc 32B][pad to 512][rank 8MB]
    unsigned long long* bp_pack = (unsigned long long*)ws;
    int*    num_pos = (int*)(ws + 8192);
    double* acc     = (double*)(ws + 8192 + 256);
    float*  rank    = (float*)(ws + 8192 + 512);

    hipMemsetAsync(ws, 0, 8192 + 512, stream);   // bp_pack + num_pos + acc

    best_prior_kernel<<<dim3(P_ / (256 * BPT), B_), 256, 0, stream>>>(
        priors, targets, bp_pack);
    match_kernel<<<dim3(P_ / (256 * PPT), B_), 256, 0, stream>>>(
        loc_data, conf_data, priors, targets, (const unsigned*)bp_pack,
        rank, num_pos, acc);
    topk_kernel<<<B_, 1024, 0, stream>>>(rank, num_pos, acc);
    finalize_kernel<<<1, 64, 0, stream>>>(num_pos, acc, (float*)d_out);
}

// Round 6
// 108.872 us; speedup vs baseline: 1.9202x; 1.9202x over previous
//
#include <hip/hip_runtime.h>
#include <stdint.h>

#define B_ 64
#define P_ 32768
#define O_ 16
#define PPT 4                 // priors per thread in match_kernel
#define BP_CHUNK 1024         // priors per block in best_prior_kernel

constexpr float OVERLAP_THRESH = 0.5f;
constexpr int   NEG_POS_RATIO  = 3;
constexpr float VAR0 = 0.1f;
constexpr float VAR1 = 0.2f;

__device__ __forceinline__ unsigned long long umax64(unsigned long long a,
                                                     unsigned long long b) {
    return a > b ? a : b;
}

// ---------------------------------------------------------------------------
// Kernel 1: best prior per (b,o) = argmax_p IoU(truth o, prior p).
// Thread (g,o) = (tid>>4, tid&15): scans BP_CHUNK/16 priors (stride 16) for
// ONE truth. Running best (in,un,p) via cross-mult compare (division-free,
// first-index tie-break). Merge: shfl_xor(16,32) within wave -> 4 wave
// leaders -> LDS plain writes -> 16 threads 4-way max -> ONE global
// atomicMax per (block,o). Pack = (iou_bits<<32)|~p (iou>=0 -> monotonic).
// bp_pack must be pre-zeroed.
// ---------------------------------------------------------------------------
__global__ __launch_bounds__(256)
void best_prior_kernel(const float* __restrict__ priors,
                       const float* __restrict__ targets,
                       unsigned long long* __restrict__ bp_pack) {
    int b   = blockIdx.y;
    int tid = threadIdx.x;
    int g   = tid >> 4;            // 0..15: prior lane
    int o   = tid & 15;            // 0..15: truth index

    const float* t = targets + ((size_t)b * O_ + o) * 5;
    float tx0 = t[0], ty0 = t[1], tx1 = t[2], ty1 = t[3];
    float ta  = (tx1 - tx0) * (ty1 - ty0);

    int pbase = blockIdx.x * BP_CHUNK + g;
    float bin_ = 0.f, bun_ = 1.f;
    int   bp_  = pbase;

    #pragma unroll 4
    for (int j = 0; j < BP_CHUNK / 16; ++j) {
        int p = pbase + j * 16;
        float4 pr = ((const float4*)priors)[p];
        float px0 = pr.x - pr.z * 0.5f, py0 = pr.y - pr.w * 0.5f;
        float px1 = pr.x + pr.z * 0.5f, py1 = pr.y + pr.w * 0.5f;
        float pa  = (px1 - px0) * (py1 - py0);
        float w = fmaxf(fminf(tx1, px1) - fmaxf(tx0, px0), 0.f);
        float h = fmaxf(fminf(ty1, py1) - fmaxf(ty0, py0), 0.f);
        float in_ = w * h;
        float un_ = ta + pa - in_;
        bool gt = in_ * bun_ > bin_ * un_;   // strict: first index wins ties
        bin_ = gt ? in_ : bin_;
        bun_ = gt ? un_ : bun_;
        bp_  = gt ? p   : bp_;
    }

    float iou = bin_ / bun_;   // IEEE f32 div: reference rounding for ordering
    unsigned long long pack =
        ((unsigned long long)__float_as_uint(iou) << 32) | (unsigned)(~bp_);

    // reduce over g: lanes sharing (lane&15) are l, l^16, l^32, l^48
    pack = umax64(pack, __shfl_xor(pack, 16, 64));
    pack = umax64(pack, __shfl_xor(pack, 32, 64));

    __shared__ unsigned long long sw[4][16];
    int lane = tid & 63, wid = tid >> 6;
    if (lane < 16) sw[wid][lane] = pack;
    __syncthreads();
    if (tid < 16) {
        unsigned long long m = umax64(umax64(sw[0][tid], sw[1][tid]),
                                      umax64(sw[2][tid], sw[3][tid]));
        atomicMax(&bp_pack[(size_t)b * O_ + tid], m);
    }
}

// ---------------------------------------------------------------------------
// Kernel 2: per (b, prior p): match, encode, smooth-L1, CE, rank_src.
// Truths/bp read via uniform (SGPR) loads — no LDS staging, no entry barrier.
// Division-free matching; truths-outer / priors-inner for ILP.
// ---------------------------------------------------------------------------
__device__ __forceinline__ float sl1(float d) {
    float ad = fabsf(d);
    return (ad < 1.f) ? 0.5f * d * d : ad - 0.5f;
}

__global__ __launch_bounds__(256)
void match_kernel(const float* __restrict__ loc_data,
                  const float* __restrict__ conf_data,
                  const float* __restrict__ priors,
                  const float* __restrict__ targets,
                  const unsigned* __restrict__ bp_lo,   // bp_pack viewed as u32
                  float* __restrict__ rank,
                  int* __restrict__ num_pos,
                  double* __restrict__ acc) {
    int b   = blockIdx.y;
    int tid = threadIdx.x;
    int p0  = blockIdx.x * (256 * PPT) + tid;
    const float* tb = targets + (size_t)b * O_ * 5;   // uniform -> s_load

    float px0[PPT], py0[PPT], px1[PPT], py1[PPT], pa[PPT];
    float cx[PPT], cy[PPT], pz[PPT], pw[PPT];
    float2 cd[PPT];
    float ib[PPT], ub[PPT];
    int   idx[PPT], fidx[PPT];
    bool  fset[PPT];

    #pragma unroll
    for (int j = 0; j < PPT; ++j) {
        int p = p0 + j * 256;
        float4 pr = ((const float4*)priors)[p];
        cd[j] = ((const float2*)conf_data)[(size_t)b * P_ + p];
        cx[j] = pr.x; cy[j] = pr.y; pz[j] = pr.z; pw[j] = pr.w;
        px0[j] = pr.x - pr.z * 0.5f; py0[j] = pr.y - pr.w * 0.5f;
        px1[j] = pr.x + pr.z * 0.5f; py1[j] = pr.y + pr.w * 0.5f;
        pa[j]  = (px1[j] - px0[j]) * (py1[j] - py0[j]);
        ib[j] = 0.f; ub[j] = 1.f; idx[j] = 0; fidx[j] = 0; fset[j] = false;
    }

    #pragma unroll
    for (int o = 0; o < O_; ++o) {
        float tx0 = tb[o * 5 + 0], ty0 = tb[o * 5 + 1];
        float tx1 = tb[o * 5 + 2], ty1 = tb[o * 5 + 3];
        float ta  = (tx1 - tx0) * (ty1 - ty0);
        int bp = (int)~bp_lo[((size_t)b * O_ + o) * 2];  // low dword (LE)
        #pragma unroll
        for (int j = 0; j < PPT; ++j) {
            float w = fmaxf(fminf(tx1, px1[j]) - fmaxf(tx0, px0[j]), 0.f);
            float h = fmaxf(fminf(ty1, py1[j]) - fmaxf(ty0, py0[j]), 0.f);
            float in_ = w * h;
            float un_ = ta + pa[j] - in_;
            bool gt = in_ * ub[j] > ib[j] * un_;
            ib[j]  = gt ? in_ : ib[j];
            ub[j]  = gt ? un_ : ub[j];
            idx[j] = gt ? o : idx[j];
            bool hit = (bp == p0 + j * 256);
            fidx[j] = hit ? o : fidx[j];
            fset[j] |= hit;
        }
    }

    double lld = 0.0, ce_pos = 0.0;
    int pc = 0;

    #pragma unroll
    for (int j = 0; j < PPT; ++j) {
        int p = p0 + j * 256;
        size_t gi = (size_t)b * P_ + p;
        bool pos = fset[j] || (2.0f * ib[j] >= ub[j]);
        int mi = fset[j] ? fidx[j] : idx[j];

        float m   = fmaxf(cd[j].x, cd[j].y);
        float ad  = fabsf(cd[j].x - cd[j].y);
        float lse = m + __logf(1.0f + __expf(-ad));
        float cgt = pos ? cd[j].y : cd[j].x;
        float ce  = lse - cgt;

        rank[gi] = pos ? 0.f : ce;

        if (pos) {
            float mx0 = tb[mi * 5 + 0], my0 = tb[mi * 5 + 1];
            float mx1 = tb[mi * 5 + 2], my1 = tb[mi * 5 + 3];
            float gcx = ((mx0 + mx1) * 0.5f - cx[j]) / (VAR0 * pz[j]);
            float gcy = ((my0 + my1) * 0.5f - cy[j]) / (VAR0 * pw[j]);
            float gw  = __logf((mx1 - mx0) / pz[j]) * (1.0f / VAR1);
            float gh  = __logf((my1 - my0) / pw[j]) * (1.0f / VAR1);
            float4 ld = ((const float4*)loc_data)[gi];
            float ll = sl1(ld.x - gcx) + sl1(ld.y - gcy) +
                       sl1(ld.z - gw)  + sl1(ld.w - gh);
            lld    += (double)ll;
            ce_pos += (double)ce;
            pc     += 1;
        }
    }

    for (int off = 32; off; off >>= 1) {
        lld    += __shfl_down(lld, off, 64);
        ce_pos += __shfl_down(ce_pos, off, 64);
        pc     += __shfl_down(pc, off, 64);
    }
    __shared__ double sll[4], sce[4];
    __shared__ int    spc[4];
    int wid = tid >> 6;
    if ((tid & 63) == 0) { sll[wid] = lld; sce[wid] = ce_pos; spc[wid] = pc; }
    __syncthreads();
    if (tid == 0) {
        double tl = sll[0] + sll[1] + sll[2] + sll[3];
        double tc = sce[0] + sce[1] + sce[2] + sce[3];
        int    tp = spc[0] + spc[1] + spc[2] + spc[3];
        if (tl != 0.0) atomicAdd(&acc[0], tl);
        if (tc != 0.0) atomicAdd(&acc[1], tc);
        if (tp)        atomicAdd(&num_pos[b], tp);
    }
}

// ---------------------------------------------------------------------------
// Kernel 3: per batch, exact top-k sum via 11/11/10-bit radix select
// (3 levels, 2048 bins). Keys register-resident. Suffix-scan: lane-local +
// wave shfl + cross-wave via LDS.
// top-k sum = sum(values > kth) + (k - count_greater) * kth  (tie-exact).
// ---------------------------------------------------------------------------
__global__ __launch_bounds__(1024)
void topk_kernel(const float* __restrict__ rank,
                 const int* __restrict__ num_pos,
                 double* __restrict__ acc) {
    int b   = blockIdx.x;
    int tid = threadIdx.x;
    int np  = num_pos[b];
    int k   = min(NEG_POS_RATIO * np, P_ - 1);
    if (k <= 0) return;

    const uint4* r4 = (const uint4*)(rank + (size_t)b * P_);
    unsigned key[32];
    #pragma unroll
    for (int j = 0; j < 8; ++j) {
        uint4 v = r4[j * 1024 + tid];
        key[j * 4 + 0] = v.x; key[j * 4 + 1] = v.y;
        key[j * 4 + 2] = v.z; key[j * 4 + 3] = v.w;
    }

    __shared__ unsigned cnt[2048];
    __shared__ unsigned wsum[16];
    __shared__ unsigned s_pre;
    __shared__ int      s_k;

    int lane = tid & 63, wid = tid >> 6;
    unsigned pre = 0;
    int kk = k;

    #pragma unroll
    for (int level = 0; level < 3; ++level) {
        const int shift = (level == 0) ? 21 : (level == 1) ? 10 : 0;
        const int hishf = (level == 1) ? 21 : 10;
        const unsigned fmask = (level == 2) ? 0x3FFu : 0x7FFu;
        const int nb = (level == 2) ? 1024 : 2048;

        cnt[tid] = 0; cnt[tid + 1024] = 0;
        __syncthreads();

        if (level == 0) {
            #pragma unroll
            for (int j = 0; j < 32; ++j)
                atomicAdd(&cnt[key[j] >> 21], 1u);
        } else {
            #pragma unroll
            for (int j = 0; j < 32; ++j) {
                unsigned u = key[j];
                if ((u >> hishf) == pre) atomicAdd(&cnt[(u >> shift) & fmask], 1u);
            }
        }
        __syncthreads();

        unsigned c1 = (2 * tid + 1 < nb) ? cnt[2 * tid + 1] : 0u;
        unsigned c0 = ((2 * tid < nb) ? cnt[2 * tid] : 0u) + c1;
        unsigned g = c0, G = g;
        #pragma unroll
        for (int off = 1; off < 64; off <<= 1) {
            unsigned r = __shfl_down(G, off, 64);
            if (lane + off < 64) G += r;
        }
        if (lane == 0) wsum[wid] = G;
        __syncthreads();
        unsigned T = 0;
        for (int w = wid + 1; w < 16; ++w) T += wsum[w];
        unsigned A  = (G - g) + T;
        unsigned S1 = A + c1;
        unsigned S0 = A + c0;
        unsigned ukk = (unsigned)kk;
        if (2 * tid + 1 < nb && S1 >= ukk && A < ukk) {
            s_pre = (unsigned)(2 * tid + 1); s_k = kk - (int)A;
        } else if (2 * tid < nb && S0 >= ukk && S1 < ukk) {
            s_pre = (unsigned)(2 * tid);     s_k = kk - (int)S1;
        }
        __syncthreads();
        pre = (pre << ((level == 2) ? 10 : 11)) | s_pre;
        kk  = s_k;
        __syncthreads();
    }

    unsigned kth = pre;
    double sum = 0.0;
    int cg = 0;
    #pragma unroll
    for (int j = 0; j < 32; ++j) {
        unsigned u = key[j];
        if (u > kth) { sum += (double)__uint_as_float(u); ++cg; }
    }
    for (int off = 32; off; off >>= 1) {
        sum += __shfl_down(sum, off, 64);
        cg  += __shfl_down(cg, off, 64);
    }
    __shared__ double ssum[16];
    __shared__ int    scg[16];
    if (lane == 0) { ssum[wid] = sum; scg[wid] = cg; }
    __syncthreads();
    if (tid == 0) {
        double tsum = 0.0; int tcg = 0;
        for (int i = 0; i < 16; ++i) { tsum += ssum[i]; tcg += scg[i]; }
        double total = tsum + (double)(k - tcg) * (double)__uint_as_float(kth);
        atomicAdd(&acc[2], total);
    }
}

// ---------------------------------------------------------------------------
// Kernel 4: finalize (wave-parallel N reduce)
// ---------------------------------------------------------------------------
__global__ void finalize_kernel(const int* __restrict__ num_pos,
                                const double* __restrict__ acc,
                                float* __restrict__ out) {
    int lane = threadIdx.x;
    int n = (lane < B_) ? num_pos[lane] : 0;
    for (int off = 32; off; off >>= 1) n += __shfl_down(n, off, 64);
    if (lane == 0) {
        double Nd = (double)n;
        out[0] = (float)(acc[0] / Nd);
        out[1] = (float)((acc[1] + acc[2]) / Nd);
    }
}

extern "C" void kernel_launch(void* const* d_in, const int* in_sizes, int n_in,
                              void* d_out, int out_size, void* d_ws, size_t ws_size,
                              hipStream_t stream) {
    const float* loc_data  = (const float*)d_in[0];
    const float* conf_data = (const float*)d_in[1];
    const float* priors    = (const float*)d_in[2];
    const float* targets   = (const float*)d_in[3];

    char* ws = (char*)d_ws;
    // layout: [bp_pack 8KB][num_pos 256B][acc 32B][pad to 512][rank 8MB]
    unsigned long long* bp_pack = (unsigned long long*)ws;
    int*    num_pos = (int*)(ws + 8192);
    double* acc     = (double*)(ws + 8192 + 256);
    float*  rank    = (float*)(ws + 8192 + 512);

    hipMemsetAsync(ws, 0, 8192 + 512, stream);   // bp_pack + num_pos + acc

    best_prior_kernel<<<dim3(P_ / BP_CHUNK, B_), 256, 0, stream>>>(
        priors, targets, bp_pack);
    match_kernel<<<dim3(P_ / (256 * PPT), B_), 256, 0, stream>>>(
        loc_data, conf_data, priors, targets, (const unsigned*)bp_pack,
        rank, num_pos, acc);
    topk_kernel<<<B_, 1024, 0, stream>>>(rank, num_pos, acc);
    finalize_kernel<<<1, 64, 0, stream>>>(num_pos, acc, (float*)d_out);
}